// Round 1
// baseline (11230.825 us; speedup 1.0000x reference)
//
#include <hip/hip_runtime.h>

// ---------------------------------------------------------------------------
// LSTM layer, T=512 B=64 I=H=1024, bf16 MFMA path.
// d_in: x[T,B,I], h0[B,H], c0[B,H], W_ih[4H,I], W_hh[4H,H], b_ih[4H], b_hh[4H]
// d_out: outputs[T,B,H] ++ hT[B,H] ++ cT[B,H]  (fp32)
// ---------------------------------------------------------------------------

typedef __attribute__((ext_vector_type(8))) short bf16x8;
typedef __attribute__((ext_vector_type(4))) short bf16x4;
typedef __attribute__((ext_vector_type(4))) float f32x4;

#define T_STEPS 512
#define BATCH   64
#define HID     1024
#define G4      4096
#define MTOT    32768   // T*B

// ws layout (bytes)
#define OFF_XPT   ((size_t)0)            // bf16 [4096][32768] transposed x-proj (+bias)
#define OFF_XB    ((size_t)268435456)    // bf16 [32768][1024] x
#define OFF_WIB   ((size_t)335544320)    // bf16 [4096][1024] W_ih
#define OFF_WHB   ((size_t)343932928)    // bf16 [4096][1024] W_hh
#define OFF_HBUF  ((size_t)352321536)    // bf16 [2][64][1024] h double buffer
#define OFF_BSUM  ((size_t)352583680)    // f32 [4096] b_ih+b_hh
#define OFF_CNT   ((size_t)352600064)    // u32 [4][512] per-row per-step barrier counters

__device__ __forceinline__ unsigned short f2bf(float f) {
  unsigned int u = __float_as_uint(f);
  u += 0x7FFFu + ((u >> 16) & 1u);
  return (unsigned short)(u >> 16);
}
__device__ __forceinline__ float bf2f(short s) {
  return __uint_as_float(((unsigned int)(unsigned short)s) << 16);
}
__device__ __forceinline__ float sigm(float x) { return 1.0f / (1.0f + __expf(-x)); }
__device__ __forceinline__ float tanh_f(float x) {
  float e = __expf(-2.0f * fabsf(x));
  float r = (1.0f - e) / (1.0f + e);
  return x < 0.0f ? -r : r;
}

// ---------------------------------------------------------------------------
__global__ void k_cast_bf16(const float* __restrict__ src,
                            unsigned short* __restrict__ dst, int n) {
  int i = (blockIdx.x * 256 + threadIdx.x) * 4;
  if (i >= n) return;
  float4 v = *(const float4*)(src + i);
  bf16x4 o;
  o[0] = (short)f2bf(v.x); o[1] = (short)f2bf(v.y);
  o[2] = (short)f2bf(v.z); o[3] = (short)f2bf(v.w);
  *(bf16x4*)(dst + i) = o;
}

__global__ void k_bias(const float* __restrict__ bi, const float* __restrict__ bh,
                       float* __restrict__ bs) {
  int i = blockIdx.x * 256 + threadIdx.x;
  if (i < G4) bs[i] = bi[i] + bh[i];
}

// ---------------------------------------------------------------------------
// x-projection GEMM: xpT[n][m] = sum_k xb[m][k]*wib[n][k] + bsum[n]  (bf16 out)
// grid 4096 = 64 n-slices x 64 m-supers; block 256 = 4 waves.
// Wave w holds 16 rows of W_ih (full K=1024) in 128 VGPRs.
__launch_bounds__(256, 2)
__global__ void k_xproj(const unsigned short* __restrict__ xb,
                        const unsigned short* __restrict__ wib,
                        const float* __restrict__ bs,
                        unsigned short* __restrict__ xpT) {
  const int lane = threadIdx.x & 63;
  const int w    = threadIdx.x >> 6;
  const int nsl  = blockIdx.x & 63;
  const int msup = blockIdx.x >> 6;
  const int col  = lane & 15;
  const int kch  = (lane >> 4) * 8;
  const int nrow = nsl * 64 + w * 16 + col;

  bf16x8 W[32];
  const unsigned short* wp = wib + (size_t)nrow * 1024 + kch;
#pragma unroll
  for (int s = 0; s < 32; ++s) W[s] = *(const bf16x8*)(wp + s * 32);

  const float bias = bs[nrow];

  for (int mc = 0; mc < 8; ++mc) {
    const int m0 = msup * 512 + mc * 64;
    f32x4 acc[4];
#pragma unroll
    for (int ms = 0; ms < 4; ++ms) acc[ms] = (f32x4){0.f, 0.f, 0.f, 0.f};

#pragma unroll
    for (int s = 0; s < 32; ++s) {
#pragma unroll
      for (int ms = 0; ms < 4; ++ms) {
        bf16x8 a = *(const bf16x8*)(xb + (size_t)(m0 + ms * 16 + col) * 1024 + s * 32 + kch);
        acc[ms] = __builtin_amdgcn_mfma_f32_16x16x32_bf16(a, W[s], acc[ms], 0, 0, 0);
      }
    }
#pragma unroll
    for (int ms = 0; ms < 4; ++ms) {
      const int mbase = m0 + ms * 16 + (lane >> 4) * 4;
      bf16x4 ov;
#pragma unroll
      for (int r = 0; r < 4; ++r) ov[r] = (short)f2bf(acc[ms][r] + bias);
      *(bf16x4*)(xpT + (size_t)nrow * 32768 + mbase) = ov;
    }
  }
}

// ---------------------------------------------------------------------------
// Persistent recurrent kernel. grid 256 = 4 batch-rows x 64 h-col slices.
// Wave w = gate w (i,f,g,o). 16 W_hh rows/wave resident in 128 VGPRs.
__launch_bounds__(256, 1)
__global__ void k_lstm(const unsigned short* __restrict__ whb,
                       const unsigned short* __restrict__ xpT,
                       const float* __restrict__ c0,
                       unsigned short* __restrict__ hbuf,
                       unsigned int* __restrict__ cnt,
                       float* __restrict__ out) {
  const int tid  = threadIdx.x;
  const int lane = tid & 63;
  const int w    = tid >> 6;            // gate index 0..3
  const int jsl  = blockIdx.x & 63;     // h-col slice
  const int brow = blockIdx.x >> 6;     // batch row 0..3
  const int b0   = brow * 16;
  const int j0   = jsl * 16;
  const int col  = lane & 15;
  const int kch  = (lane >> 4) * 8;

  __shared__ float glds[4][16][17];

  // W_hh fragment registers: row = w*1024 + j0 + col, all K
  bf16x8 W[32];
  const unsigned short* wp = whb + (size_t)(w * 1024 + j0 + col) * 1024 + kch;
#pragma unroll
  for (int s = 0; s < 32; ++s) W[s] = *(const bf16x8*)(wp + s * 32);

  // cell state: thread tid -> (batch-local bl, col cc)
  const int bl = tid >> 4, cc = tid & 15;
  float c = c0[(b0 + bl) * 1024 + j0 + cc];

  unsigned int* mycnt = cnt + brow * 512;
  const unsigned short* xprow = xpT + (size_t)(w * 1024 + j0 + col) * 32768 + b0 + (lane >> 4) * 4;

  for (int t = 0; t < T_STEPS; ++t) {
    if (t > 0 && tid == 0) {
      while (__hip_atomic_load(&mycnt[t - 1], __ATOMIC_RELAXED, __HIP_MEMORY_SCOPE_AGENT) < 64u) {}
    }
    __syncthreads();
    __builtin_amdgcn_fence(__ATOMIC_ACQUIRE, "agent");

    // per-step x-proj slice (independent of h: issue early)
    bf16x4 xv = *(const bf16x4*)(xprow + t * 64);

    const unsigned short* hr = hbuf + (t & 1) * (BATCH * HID) + (size_t)(b0 + col) * 1024 + kch;
    f32x4 acc0 = (f32x4){0.f, 0.f, 0.f, 0.f};
    f32x4 acc1 = (f32x4){0.f, 0.f, 0.f, 0.f};
#pragma unroll
    for (int s = 0; s < 32; s += 2) {
      bf16x8 a0 = *(const bf16x8*)(hr + s * 32);
      bf16x8 a1 = *(const bf16x8*)(hr + (s + 1) * 32);
      acc0 = __builtin_amdgcn_mfma_f32_16x16x32_bf16(a0, W[s],     acc0, 0, 0, 0);
      acc1 = __builtin_amdgcn_mfma_f32_16x16x32_bf16(a1, W[s + 1], acc1, 0, 0, 0);
    }

#pragma unroll
    for (int r = 0; r < 4; ++r) {
      float v = (acc0[r] + acc1[r]) + bf2f(xv[r]);
      float g = (w == 2) ? tanh_f(v) : sigm(v);
      glds[w][(lane >> 4) * 4 + r][col] = g;
    }
    __syncthreads();

    float ig = glds[0][bl][cc], fg = glds[1][bl][cc];
    float gg = glds[2][bl][cc], og = glds[3][bl][cc];
    c = fg * c + ig * gg;
    float h = og * tanh_f(c);

    const int hoff = (b0 + bl) * 1024 + j0 + cc;
    out[(size_t)t * (BATCH * HID) + hoff] = h;
    hbuf[((t & 1) ^ 1) * (BATCH * HID) + hoff] = f2bf(h);
    if (t == T_STEPS - 1) {
      out[(size_t)T_STEPS * (BATCH * HID) + hoff] = h;                 // hT
      out[(size_t)T_STEPS * (BATCH * HID) + (BATCH * HID) + hoff] = c; // cT
    }
    __syncthreads();  // all stores drained (vmcnt(0) before s_barrier)
    if (tid == 0) {
      __hip_atomic_fetch_add(&mycnt[t], 1u, __ATOMIC_RELEASE, __HIP_MEMORY_SCOPE_AGENT);
    }
  }
}

// ---------------------------------------------------------------------------
extern "C" void kernel_launch(void* const* d_in, const int* in_sizes, int n_in,
                              void* d_out, int out_size, void* d_ws, size_t ws_size,
                              hipStream_t stream) {
  const float* x   = (const float*)d_in[0];
  const float* h0  = (const float*)d_in[1];
  const float* c0  = (const float*)d_in[2];
  const float* Wih = (const float*)d_in[3];
  const float* Whh = (const float*)d_in[4];
  const float* bih = (const float*)d_in[5];
  const float* bhh = (const float*)d_in[6];
  float* out = (float*)d_out;
  char* ws = (char*)d_ws;

  unsigned short* xpT  = (unsigned short*)(ws + OFF_XPT);
  unsigned short* xb   = (unsigned short*)(ws + OFF_XB);
  unsigned short* wib  = (unsigned short*)(ws + OFF_WIB);
  unsigned short* whb  = (unsigned short*)(ws + OFF_WHB);
  unsigned short* hbuf = (unsigned short*)(ws + OFF_HBUF);
  float*          bsum = (float*)(ws + OFF_BSUM);
  unsigned int*   cnt  = (unsigned int*)(ws + OFF_CNT);

  hipMemsetAsync(cnt, 0, 4 * 512 * sizeof(unsigned int), stream);

  k_cast_bf16<<<dim3(32768), dim3(256), 0, stream>>>(x, xb, T_STEPS * BATCH * HID);
  k_cast_bf16<<<dim3(4096),  dim3(256), 0, stream>>>(Wih, wib, G4 * HID);
  k_cast_bf16<<<dim3(4096),  dim3(256), 0, stream>>>(Whh, whb, G4 * HID);
  k_cast_bf16<<<dim3(64),    dim3(256), 0, stream>>>(h0, hbuf, BATCH * HID);
  k_bias<<<dim3(16), dim3(256), 0, stream>>>(bih, bhh, bsum);

  k_xproj<<<dim3(4096), dim3(256), 0, stream>>>(xb, wib, bsum, xpT);
  k_lstm<<<dim3(256), dim3(256), 0, stream>>>(whb, xpT, c0, hbuf, cnt, out);
}

// Round 2
// 7736.528 us; speedup vs baseline: 1.4517x; 1.4517x over previous
//
#include <hip/hip_runtime.h>

// ---------------------------------------------------------------------------
// LSTM layer, T=512 B=64 I=H=1024, bf16 MFMA path.
// d_in: x[T,B,I], h0[B,H], c0[B,H], W_ih[4H,I], W_hh[4H,H], b_ih[4H], b_hh[4H]
// d_out: outputs[T,B,H] ++ hT[B,H] ++ cT[B,H]  (fp32)
//
// Round 2: removed all agent-scope C++ fences (they emit whole-L2
// writeback/invalidate per WG per step on multi-XCD gfx950 — the 17.9us/step
// killer, and they forced W_hh re-loads every step: VGPR_Count was 84 < 128
// needed). h exchange + flags now use per-access agent-scope relaxed atomics
// (sc0/sc1 fine-grained coherence via LLC). Per-WG flag array replaces the
// contended counter.
// ---------------------------------------------------------------------------

typedef __attribute__((ext_vector_type(8))) short bf16x8;
typedef __attribute__((ext_vector_type(4))) short bf16x4;
typedef __attribute__((ext_vector_type(4))) float f32x4;
typedef unsigned long long u64;

#define T_STEPS 512
#define BATCH   64
#define HID     1024
#define G4      4096
#define MTOT    32768   // T*B

// ws layout (bytes)
#define OFF_XPT   ((size_t)0)            // bf16 [4096][32768] transposed x-proj (+bias)
#define OFF_XB    ((size_t)268435456)    // bf16 [32768][1024] x
#define OFF_WIB   ((size_t)335544320)    // bf16 [4096][1024] W_ih
#define OFF_WHB   ((size_t)343932928)    // bf16 [4096][1024] W_hh
#define OFF_HBUF  ((size_t)352321536)    // bf16 [2][64][1024] h double buffer
#define OFF_BSUM  ((size_t)352583680)    // f32 [4096] b_ih+b_hh
#define OFF_FLG   ((size_t)352600064)    // u32 [4][512][64] per-(row,step,wg) flags

__device__ __forceinline__ unsigned short f2bf(float f) {
  unsigned int u = __float_as_uint(f);
  u += 0x7FFFu + ((u >> 16) & 1u);
  return (unsigned short)(u >> 16);
}
__device__ __forceinline__ float bf2f(short s) {
  return __uint_as_float(((unsigned int)(unsigned short)s) << 16);
}
__device__ __forceinline__ float sigm(float x) { return 1.0f / (1.0f + __expf(-x)); }
__device__ __forceinline__ float tanh_f(float x) {
  float e = __expf(-2.0f * fabsf(x));
  float r = (1.0f - e) / (1.0f + e);
  return x < 0.0f ? -r : r;
}

// ---------------------------------------------------------------------------
__global__ void k_cast_bf16(const float* __restrict__ src,
                            unsigned short* __restrict__ dst, int n) {
  int i = (blockIdx.x * 256 + threadIdx.x) * 4;
  if (i >= n) return;
  float4 v = *(const float4*)(src + i);
  bf16x4 o;
  o[0] = (short)f2bf(v.x); o[1] = (short)f2bf(v.y);
  o[2] = (short)f2bf(v.z); o[3] = (short)f2bf(v.w);
  *(bf16x4*)(dst + i) = o;
}

__global__ void k_bias(const float* __restrict__ bi, const float* __restrict__ bh,
                       float* __restrict__ bs) {
  int i = blockIdx.x * 256 + threadIdx.x;
  if (i < G4) bs[i] = bi[i] + bh[i];
}

// ---------------------------------------------------------------------------
// x-projection GEMM: xpT[n][m] = sum_k xb[m][k]*wib[n][k] + bsum[n]  (bf16 out)
// grid 4096 = 64 n-slices x 64 m-supers; block 256 = 4 waves.
__launch_bounds__(256, 2)
__global__ void k_xproj(const unsigned short* __restrict__ xb,
                        const unsigned short* __restrict__ wib,
                        const float* __restrict__ bs,
                        unsigned short* __restrict__ xpT) {
  const int lane = threadIdx.x & 63;
  const int w    = threadIdx.x >> 6;
  const int nsl  = blockIdx.x & 63;
  const int msup = blockIdx.x >> 6;
  const int col  = lane & 15;
  const int kch  = (lane >> 4) * 8;
  const int nrow = nsl * 64 + w * 16 + col;

  bf16x8 W[32];
  const unsigned short* wp = wib + (size_t)nrow * 1024 + kch;
#pragma unroll
  for (int s = 0; s < 32; ++s) W[s] = *(const bf16x8*)(wp + s * 32);

  const float bias = bs[nrow];

  for (int mc = 0; mc < 8; ++mc) {
    const int m0 = msup * 512 + mc * 64;
    f32x4 acc[4];
#pragma unroll
    for (int ms = 0; ms < 4; ++ms) acc[ms] = (f32x4){0.f, 0.f, 0.f, 0.f};

#pragma unroll
    for (int s = 0; s < 32; ++s) {
#pragma unroll
      for (int ms = 0; ms < 4; ++ms) {
        bf16x8 a = *(const bf16x8*)(xb + (size_t)(m0 + ms * 16 + col) * 1024 + s * 32 + kch);
        acc[ms] = __builtin_amdgcn_mfma_f32_16x16x32_bf16(a, W[s], acc[ms], 0, 0, 0);
      }
    }
#pragma unroll
    for (int ms = 0; ms < 4; ++ms) {
      const int mbase = m0 + ms * 16 + (lane >> 4) * 4;
      bf16x4 ov;
#pragma unroll
      for (int r = 0; r < 4; ++r) ov[r] = (short)f2bf(acc[ms][r] + bias);
      *(bf16x4*)(xpT + (size_t)nrow * 32768 + mbase) = ov;
    }
  }
}

// ---------------------------------------------------------------------------
// Persistent recurrent kernel. grid 256 = 4 batch-rows x 64 h-col slices.
// Wave w = gate w (i,f,g,o). 16 W_hh rows/wave resident in 128 VGPRs.
// h exchange via agent-coherent (sc0/sc1) fine-grained atomics through LLC;
// NO fences (they would flush L2 and evict W from registers).
__launch_bounds__(256, 1)
__global__ void k_lstm(const unsigned short* __restrict__ whb,
                       const unsigned short* __restrict__ xpT,
                       const float* __restrict__ c0,
                       unsigned short* __restrict__ hbuf,
                       unsigned int* __restrict__ flags,
                       float* __restrict__ out) {
  const int tid  = threadIdx.x;
  const int lane = tid & 63;
  const int w    = tid >> 6;            // gate index 0..3
  const int jsl  = blockIdx.x & 63;     // h-col slice
  const int brow = blockIdx.x >> 6;     // batch row 0..3
  const int b0   = brow * 16;
  const int j0   = jsl * 16;
  const int col  = lane & 15;
  const int kch  = (lane >> 4) * 8;

  __shared__ float glds[4][16][17];
  __shared__ unsigned short hs[16][16];

  // W_hh fragment registers: row = w*1024 + j0 + col, all K (128 VGPRs)
  bf16x8 W[32];
  const unsigned short* wp = whb + (size_t)(w * 1024 + j0 + col) * 1024 + kch;
#pragma unroll
  for (int s = 0; s < 32; ++s) W[s] = *(const bf16x8*)(wp + s * 32);

  // cell state: thread tid -> (batch-local bl, col cc)
  const int bl = tid >> 4, cc = tid & 15;
  float c = c0[(b0 + bl) * 1024 + j0 + cc];

  const unsigned short* xprow =
      xpT + (size_t)(w * 1024 + j0 + col) * 32768 + b0 + (lane >> 4) * 4;
  unsigned int* rowflags = flags + (size_t)brow * 512 * 64;

  for (int t = 0; t < T_STEPS; ++t) {
    // ---- wait for previous step's h (64 producer flags of this batch-row) --
    if (t > 0 && tid < 64) {
      const unsigned int* fp = rowflags + (size_t)(t - 1) * 64 + lane;
      for (;;) {
        unsigned int v = __hip_atomic_load(fp, __ATOMIC_RELAXED,
                                           __HIP_MEMORY_SCOPE_AGENT);
        if (__all(v != 0u)) break;
      }
    }
    __syncthreads();

    // per-step x-proj slice (plain cached load; produced before this kernel)
    bf16x4 xv = *(const bf16x4*)(xprow + (size_t)t * 64);

    // ---- recurrent GEMM: A = h[t&1] via agent-coherent loads (LLC) --------
    const u64* hr = (const u64*)(hbuf) + ((size_t)(t & 1) * (BATCH * HID) +
                                          (size_t)(b0 + col) * 1024 + kch) / 4;
    f32x4 acc0 = (f32x4){0.f, 0.f, 0.f, 0.f};
    f32x4 acc1 = (f32x4){0.f, 0.f, 0.f, 0.f};
#pragma unroll
    for (int s = 0; s < 32; s += 2) {
      union { u64 q[2]; bf16x8 v; } a0, a1;
      a0.q[0] = __hip_atomic_load(hr + s * 8 + 0, __ATOMIC_RELAXED, __HIP_MEMORY_SCOPE_AGENT);
      a0.q[1] = __hip_atomic_load(hr + s * 8 + 1, __ATOMIC_RELAXED, __HIP_MEMORY_SCOPE_AGENT);
      a1.q[0] = __hip_atomic_load(hr + s * 8 + 8, __ATOMIC_RELAXED, __HIP_MEMORY_SCOPE_AGENT);
      a1.q[1] = __hip_atomic_load(hr + s * 8 + 9, __ATOMIC_RELAXED, __HIP_MEMORY_SCOPE_AGENT);
      acc0 = __builtin_amdgcn_mfma_f32_16x16x32_bf16(a0.v, W[s],     acc0, 0, 0, 0);
      acc1 = __builtin_amdgcn_mfma_f32_16x16x32_bf16(a1.v, W[s + 1], acc1, 0, 0, 0);
    }

#pragma unroll
    for (int r = 0; r < 4; ++r) {
      float v = (acc0[r] + acc1[r]) + bf2f(xv[r]);
      float g = (w == 2) ? tanh_f(v) : sigm(v);
      glds[w][(lane >> 4) * 4 + r][col] = g;
    }
    __syncthreads();

    float ig = glds[0][bl][cc], fg = glds[1][bl][cc];
    float gg = glds[2][bl][cc], og = glds[3][bl][cc];
    c = fg * c + ig * gg;
    float h = og * tanh_f(c);

    const int hoff = (b0 + bl) * 1024 + j0 + cc;
    out[(size_t)t * (BATCH * HID) + hoff] = h;
    if (t == T_STEPS - 1) {
      out[(size_t)T_STEPS * (BATCH * HID) + hoff] = h;                 // hT
      out[(size_t)T_STEPS * (BATCH * HID) + (BATCH * HID) + hoff] = c; // cT
    }
    hs[bl][cc] = f2bf(h);
    __syncthreads();

    // ---- publish h for step t+1 (write-through to LLC), then flag ---------
    if (tid < 64) {
      const int sb = tid >> 2, sq = tid & 3;
      u64 pv = *(const u64*)&hs[sb][sq * 4];
      u64* dst = (u64*)(hbuf) + (((size_t)((t & 1) ^ 1)) * (BATCH * HID) +
                                 (size_t)(b0 + sb) * 1024 + j0 + sq * 4) / 4;
      __hip_atomic_store(dst, pv, __ATOMIC_RELAXED, __HIP_MEMORY_SCOPE_AGENT);
    }
    __syncthreads();  // emits s_waitcnt vmcnt(0) before s_barrier: h drained
    if (tid == 0) {
      __hip_atomic_store(rowflags + (size_t)t * 64 + jsl, 1u,
                         __ATOMIC_RELAXED, __HIP_MEMORY_SCOPE_AGENT);
    }
  }
}

// ---------------------------------------------------------------------------
extern "C" void kernel_launch(void* const* d_in, const int* in_sizes, int n_in,
                              void* d_out, int out_size, void* d_ws, size_t ws_size,
                              hipStream_t stream) {
  const float* x   = (const float*)d_in[0];
  const float* h0  = (const float*)d_in[1];
  const float* c0  = (const float*)d_in[2];
  const float* Wih = (const float*)d_in[3];
  const float* Whh = (const float*)d_in[4];
  const float* bih = (const float*)d_in[5];
  const float* bhh = (const float*)d_in[6];
  float* out = (float*)d_out;
  char* ws = (char*)d_ws;

  unsigned short* xpT  = (unsigned short*)(ws + OFF_XPT);
  unsigned short* xb   = (unsigned short*)(ws + OFF_XB);
  unsigned short* wib  = (unsigned short*)(ws + OFF_WIB);
  unsigned short* whb  = (unsigned short*)(ws + OFF_WHB);
  unsigned short* hbuf = (unsigned short*)(ws + OFF_HBUF);
  float*          bsum = (float*)(ws + OFF_BSUM);
  unsigned int*   flg  = (unsigned int*)(ws + OFF_FLG);

  hipMemsetAsync(flg, 0, 4 * 512 * 64 * sizeof(unsigned int), stream);

  k_cast_bf16<<<dim3(32768), dim3(256), 0, stream>>>(x, xb, T_STEPS * BATCH * HID);
  k_cast_bf16<<<dim3(4096),  dim3(256), 0, stream>>>(Wih, wib, G4 * HID);
  k_cast_bf16<<<dim3(4096),  dim3(256), 0, stream>>>(Whh, whb, G4 * HID);
  k_cast_bf16<<<dim3(64),    dim3(256), 0, stream>>>(h0, hbuf, BATCH * HID);
  k_bias<<<dim3(16), dim3(256), 0, stream>>>(bih, bhh, bsum);

  k_xproj<<<dim3(4096), dim3(256), 0, stream>>>(xb, wib, bsum, xpT);
  k_lstm<<<dim3(256), dim3(256), 0, stream>>>(whb, xpT, c0, hbuf, flg, out);
}

// Round 3
// 6064.071 us; speedup vs baseline: 1.8520x; 1.2758x over previous
//
#include <hip/hip_runtime.h>

// ---------------------------------------------------------------------------
// LSTM layer, T=512 B=64 I=H=1024, bf16 MFMA path.
// d_in: x[T,B,I], h0[B,H], c0[B,H], W_ih[4H,I], W_hh[4H,H], b_ih[4H], b_hh[4H]
// d_out: outputs[T,B,H] ++ hT[B,H] ++ cT[B,H]  (fp32)
//
// Round 3:
//  - W_hh staged in LDS (128KB/WG) -- VGPR_Count=88 proved the compiler was
//    re-loading W from global every step.
//  - h exchanged through a write-once ring (one 128KB slot per timestep):
//    producers publish via sc1 write-through stores, consumers use NORMAL
//    cached loads (each address written once before any read; L2 invalidated
//    at kernel start) -- kills the 8MB/step all-LLC h traffic of round 2.
//  - Ring lives where xb was; xb (bf16 x) now uses d_out's first 64MB as
//    scratch (fully consumed by k_xproj before k_lstm writes outputs).
//  - out[] stores issued AFTER the h publish + flag (they drained inside the
//    pre-flag vmcnt(0) before); xpT slice prefetched one step ahead.
// ---------------------------------------------------------------------------

typedef __attribute__((ext_vector_type(8))) short bf16x8;
typedef __attribute__((ext_vector_type(4))) short bf16x4;
typedef __attribute__((ext_vector_type(4))) float f32x4;
typedef unsigned long long u64;

#define T_STEPS 512
#define BATCH   64
#define HID     1024
#define G4      4096
#define BH      (BATCH * HID)

// ws layout (bytes)
#define OFF_XPT   ((size_t)0)            // bf16 [4096][32768] transposed x-proj (+bias)
#define OFF_RING  ((size_t)268435456)    // bf16 [512][64][1024] h ring (slot t = input of step t)
#define OFF_WIB   ((size_t)335544320)    // bf16 [4096][1024] W_ih
#define OFF_WHB   ((size_t)343932928)    // bf16 [4096][1024] W_hh
#define OFF_BSUM  ((size_t)352321536)    // f32 [4096] b_ih+b_hh
#define OFF_FLG   ((size_t)352337920)    // u32 [4][512][64] per-(row,step,wg) flags

__device__ __forceinline__ unsigned short f2bf(float f) {
  unsigned int u = __float_as_uint(f);
  u += 0x7FFFu + ((u >> 16) & 1u);
  return (unsigned short)(u >> 16);
}
__device__ __forceinline__ float bf2f(short s) {
  return __uint_as_float(((unsigned int)(unsigned short)s) << 16);
}
__device__ __forceinline__ float sigm(float x) { return 1.0f / (1.0f + __expf(-x)); }
__device__ __forceinline__ float tanh_f(float x) {
  float e = __expf(-2.0f * fabsf(x));
  float r = (1.0f - e) / (1.0f + e);
  return x < 0.0f ? -r : r;
}

// ---------------------------------------------------------------------------
__global__ void k_cast_bf16(const float* __restrict__ src,
                            unsigned short* __restrict__ dst, int n) {
  int i = (blockIdx.x * 256 + threadIdx.x) * 4;
  if (i >= n) return;
  float4 v = *(const float4*)(src + i);
  bf16x4 o;
  o[0] = (short)f2bf(v.x); o[1] = (short)f2bf(v.y);
  o[2] = (short)f2bf(v.z); o[3] = (short)f2bf(v.w);
  *(bf16x4*)(dst + i) = o;
}

__global__ void k_bias(const float* __restrict__ bi, const float* __restrict__ bh,
                       float* __restrict__ bs) {
  int i = blockIdx.x * 256 + threadIdx.x;
  if (i < G4) bs[i] = bi[i] + bh[i];
}

// ---------------------------------------------------------------------------
// x-projection GEMM: xpT[n][m] = sum_k xb[m][k]*wib[n][k] + bsum[n]  (bf16 out)
// grid 4096 = 64 n-slices x 64 m-supers; block 256 = 4 waves.
__launch_bounds__(256, 2)
__global__ void k_xproj(const unsigned short* __restrict__ xb,
                        const unsigned short* __restrict__ wib,
                        const float* __restrict__ bs,
                        unsigned short* __restrict__ xpT) {
  const int lane = threadIdx.x & 63;
  const int w    = threadIdx.x >> 6;
  const int nsl  = blockIdx.x & 63;
  const int msup = blockIdx.x >> 6;
  const int col  = lane & 15;
  const int kch  = (lane >> 4) * 8;
  const int nrow = nsl * 64 + w * 16 + col;

  bf16x8 W[32];
  const unsigned short* wp = wib + (size_t)nrow * 1024 + kch;
#pragma unroll
  for (int s = 0; s < 32; ++s) W[s] = *(const bf16x8*)(wp + s * 32);

  const float bias = bs[nrow];

  for (int mc = 0; mc < 8; ++mc) {
    const int m0 = msup * 512 + mc * 64;
    f32x4 acc[4];
#pragma unroll
    for (int ms = 0; ms < 4; ++ms) acc[ms] = (f32x4){0.f, 0.f, 0.f, 0.f};

#pragma unroll
    for (int s = 0; s < 32; ++s) {
#pragma unroll
      for (int ms = 0; ms < 4; ++ms) {
        bf16x8 a = *(const bf16x8*)(xb + (size_t)(m0 + ms * 16 + col) * 1024 + s * 32 + kch);
        acc[ms] = __builtin_amdgcn_mfma_f32_16x16x32_bf16(a, W[s], acc[ms], 0, 0, 0);
      }
    }
#pragma unroll
    for (int ms = 0; ms < 4; ++ms) {
      const int mbase = m0 + ms * 16 + (lane >> 4) * 4;
      bf16x4 ov;
#pragma unroll
      for (int r = 0; r < 4; ++r) ov[r] = (short)f2bf(acc[ms][r] + bias);
      *(bf16x4*)(xpT + (size_t)nrow * 32768 + mbase) = ov;
    }
  }
}

// ---------------------------------------------------------------------------
// Persistent recurrent kernel. grid 256 = 4 batch-rows x 64 h-col slices.
// Wave w = gate w (i,f,g,o). W_hh slice in LDS (128KB). h via write-once ring.
__launch_bounds__(256, 1)
__global__ void k_lstm(const unsigned short* __restrict__ whb,
                       const unsigned short* __restrict__ xpT,
                       const float* __restrict__ c0,
                       unsigned short* __restrict__ ring,
                       unsigned int* __restrict__ flags,
                       float* __restrict__ out) {
  const int tid  = threadIdx.x;
  const int lane = tid & 63;
  const int w    = tid >> 6;            // gate index 0..3
  const int jsl  = blockIdx.x & 63;     // h-col slice
  const int brow = blockIdx.x >> 6;     // batch row 0..3
  const int b0   = brow * 16;
  const int j0   = jsl * 16;
  const int col  = lane & 15;
  const int kch  = (lane >> 4) * 8;

  __shared__ bf16x8 WL[4][32][64];      // 128 KB: W_hh fragments
  __shared__ float glds[4][16][17];
  __shared__ unsigned short hs[16][16];

  // stage W_hh fragments into LDS (each thread loads exactly what it reads back)
  {
    const unsigned short* wp = whb + (size_t)(w * 1024 + j0 + col) * 1024 + kch;
#pragma unroll 4
    for (int s = 0; s < 32; ++s) WL[w][s][lane] = *(const bf16x8*)(wp + s * 32);
  }

  const int bl = tid >> 4, cc = tid & 15;
  float c = c0[(b0 + bl) * 1024 + j0 + cc];

  const unsigned short* xprow =
      xpT + (size_t)(w * 1024 + j0 + col) * 32768 + b0 + (lane >> 4) * 4;
  unsigned int* rowflags = flags + (size_t)brow * 512 * 64;

  __syncthreads();  // W staged

  bf16x4 xv = *(const bf16x4*)(xprow);  // step-0 x-proj slice

  for (int t = 0; t < T_STEPS; ++t) {
    // ---- wait for ring slot t (produced at step t-1; slot 0 = h0) ---------
    if (t > 0 && tid < 64) {
      const unsigned int* fp = rowflags + (size_t)(t - 1) * 64 + lane;
      for (;;) {
        unsigned int v = __hip_atomic_load(fp, __ATOMIC_RELAXED,
                                           __HIP_MEMORY_SCOPE_AGENT);
        if (__all(v != 0u)) break;
      }
    }
    __syncthreads();  // #1

    // prefetch next step's x-proj slice (static data, off critical path)
    bf16x4 xv_next = xv;
    if (t < T_STEPS - 1) xv_next = *(const bf16x4*)(xprow + (size_t)(t + 1) * 64);

    // ---- recurrent GEMM: A = ring slot t (normal cached loads) ------------
    const unsigned short* hr =
        ring + (size_t)t * BH + (size_t)(b0 + col) * 1024 + kch;
    f32x4 acc0 = (f32x4){0.f, 0.f, 0.f, 0.f};
    f32x4 acc1 = (f32x4){0.f, 0.f, 0.f, 0.f};
#pragma unroll
    for (int s = 0; s < 32; s += 2) {
      bf16x8 a0 = *(const bf16x8*)(hr + s * 32);
      bf16x8 a1 = *(const bf16x8*)(hr + (s + 1) * 32);
      acc0 = __builtin_amdgcn_mfma_f32_16x16x32_bf16(a0, WL[w][s][lane],     acc0, 0, 0, 0);
      acc1 = __builtin_amdgcn_mfma_f32_16x16x32_bf16(a1, WL[w][s + 1][lane], acc1, 0, 0, 0);
    }

#pragma unroll
    for (int r = 0; r < 4; ++r) {
      float v = (acc0[r] + acc1[r]) + bf2f(xv[r]);
      float g = (w == 2) ? tanh_f(v) : sigm(v);
      glds[w][(lane >> 4) * 4 + r][col] = g;
    }
    xv = xv_next;
    __syncthreads();  // #2

    float ig = glds[0][bl][cc], fg = glds[1][bl][cc];
    float gg = glds[2][bl][cc], og = glds[3][bl][cc];
    c = fg * c + ig * gg;
    float h = og * tanh_f(c);
    hs[bl][cc] = f2bf(h);
    __syncthreads();  // #3

    // ---- publish h into ring slot t+1 (sc1 write-through) + flag ----------
    if (tid < 64) {
      if (t < T_STEPS - 1) {
        const int sb = tid >> 2, sq = tid & 3;
        u64 pv = *(const u64*)&hs[sb][sq * 4];
        u64* dst = (u64*)(ring) + ((size_t)(t + 1) * BH +
                                   (size_t)(b0 + sb) * 1024 + j0 + sq * 4) / 4;
        __hip_atomic_store(dst, pv, __ATOMIC_RELAXED, __HIP_MEMORY_SCOPE_AGENT);
        asm volatile("s_waitcnt vmcnt(0)" ::: "memory");  // drain publish only
        if (tid == 0) {
          __hip_atomic_store(rowflags + (size_t)t * 64 + jsl, 1u,
                             __ATOMIC_RELAXED, __HIP_MEMORY_SCOPE_AGENT);
        }
      }
    }

    // ---- outputs (off the signalling path; drained at next #1) ------------
    const int hoff = (b0 + bl) * 1024 + j0 + cc;
    out[(size_t)t * BH + hoff] = h;
    if (t == T_STEPS - 1) {
      out[(size_t)T_STEPS * BH + hoff] = h;       // hT
      out[(size_t)T_STEPS * BH + BH + hoff] = c;  // cT
    }
  }
}

// ---------------------------------------------------------------------------
extern "C" void kernel_launch(void* const* d_in, const int* in_sizes, int n_in,
                              void* d_out, int out_size, void* d_ws, size_t ws_size,
                              hipStream_t stream) {
  const float* x   = (const float*)d_in[0];
  const float* h0  = (const float*)d_in[1];
  const float* c0  = (const float*)d_in[2];
  const float* Wih = (const float*)d_in[3];
  const float* Whh = (const float*)d_in[4];
  const float* bih = (const float*)d_in[5];
  const float* bhh = (const float*)d_in[6];
  float* out = (float*)d_out;
  char* ws = (char*)d_ws;

  unsigned short* xpT  = (unsigned short*)(ws + OFF_XPT);
  unsigned short* ring = (unsigned short*)(ws + OFF_RING);
  unsigned short* wib  = (unsigned short*)(ws + OFF_WIB);
  unsigned short* whb  = (unsigned short*)(ws + OFF_WHB);
  float*          bsum = (float*)(ws + OFF_BSUM);
  unsigned int*   flg  = (unsigned int*)(ws + OFF_FLG);

  // bf16 x lives in d_out's first 64MB: fully consumed by k_xproj before
  // k_lstm starts writing outputs (kernels are stream-ordered).
  unsigned short* xb = (unsigned short*)d_out;

  hipMemsetAsync(flg, 0, 4 * 512 * 64 * sizeof(unsigned int), stream);

  k_cast_bf16<<<dim3(32768), dim3(256), 0, stream>>>(x, xb, T_STEPS * BATCH * HID);
  k_cast_bf16<<<dim3(4096),  dim3(256), 0, stream>>>(Wih, wib, G4 * HID);
  k_cast_bf16<<<dim3(4096),  dim3(256), 0, stream>>>(Whh, whb, G4 * HID);
  k_cast_bf16<<<dim3(64),    dim3(256), 0, stream>>>(h0, ring, BATCH * HID);  // slot 0
  k_bias<<<dim3(16), dim3(256), 0, stream>>>(bih, bhh, bsum);

  k_xproj<<<dim3(4096), dim3(256), 0, stream>>>(xb, wib, bsum, xpT);
  k_lstm<<<dim3(256), dim3(256), 0, stream>>>(whb, xpT, c0, ring, flg, out);
}